// Round 12
// baseline (1052.542 us; speedup 1.0000x reference)
//
#include <hip/hip_runtime.h>
#include <cstdint>

constexpr int N_NODES = 5461;

using f16x8 = __attribute__((ext_vector_type(8))) _Float16;
using f32x4 = __attribute__((ext_vector_type(4))) float;

typedef const __attribute__((address_space(1))) unsigned int* gas_p;
typedef __attribute__((address_space(3))) unsigned int* las_p;

__device__ __forceinline__ float sigm(float v) { return 1.0f / (1.0f + __expf(-v)); }

__constant__ int d_STARTS[8] = {0, 1, 5, 21, 85, 341, 1365, 5461};

// ================= split-fp16 MFMA GEMM tile (device body; verified r8) =================
// 512 threads = 8 waves (2M x 4N), wave tile 64x32, block tile 128x128, K=512, 16 steps.
// LDS chunk-XOR swizzle: row r's 16B chunk c at slot c^((r>>1)&3); staged via
// inverse-permuted GLOBAL source (LDS dest linear); read slot kg^((rsel>>1)&3). 0 conflicts.
struct GSet {
    const _Float16 *Ah, *Al;
    const _Float16 *BhL, *BlL, *BhV, *BlV;
    const float *biasL, *biasV;
    float* Y;
    const int* permA;      // null => identity
    int nL, M, Nout;
};

__device__ void gemm_tile(const GSet& S, int tx, int bn)
{
    const int nTl = (S.nL + 127) >> 7;
    int rowBase, rowEnd;
    const _Float16 *Bh, *Bl;
    const float* bias;
    if (tx < nTl) {
        rowBase = tx << 7; rowEnd = S.nL;
        Bh = S.BhL; Bl = S.BlL; bias = S.biasL;
    } else {
        rowBase = S.nL + ((tx - nTl) << 7); rowEnd = S.M;
        Bh = S.BhV; Bl = S.BlV; bias = S.biasV;
    }
    if (rowBase >= rowEnd) return;

    __shared__ _Float16 AsH[2][128 * 32];
    __shared__ _Float16 AsL[2][128 * 32];
    __shared__ _Float16 BsH[2][128 * 32];
    __shared__ _Float16 BsL[2][128 * 32];

    const int tid = threadIdx.x;
    const int wid = tid >> 6;
    const int lane = tid & 63;
    const int wm = (wid >> 2) * 64;
    const int wn = (wid & 3) * 32;
    const int rsel = lane & 15;
    const int kg = lane >> 4;
    const int lrow = lane >> 2;
    const int csrc = ((lane & 3) ^ ((lane >> 3) & 3)) * 8;
    int aR = rowBase + wid * 16 + lrow; if (aR > rowEnd - 1) aR = rowEnd - 1;
    const int a0 = S.permA ? S.permA[aR] : aR;
    const _Float16* gAh = S.Ah + (size_t)a0 * 512 + csrc;
    const _Float16* gAl = S.Al + (size_t)a0 * 512 + csrc;
    const _Float16* gBh = Bh + (size_t)(bn + wid * 16 + lrow) * 512 + csrc;
    const _Float16* gBl = Bl + (size_t)(bn + wid * 16 + lrow) * 512 + csrc;

    f32x4 acc0[4][2] = {};
    f32x4 acc1[4][2] = {};

    auto stage = [&](int k0, int b) {
        __builtin_amdgcn_global_load_lds((gas_p)(const void*)(gAh + k0), (las_p)(void*)(&AsH[b][wid * 512]), 16, 0, 0);
        __builtin_amdgcn_global_load_lds((gas_p)(const void*)(gAl + k0), (las_p)(void*)(&AsL[b][wid * 512]), 16, 0, 0);
        __builtin_amdgcn_global_load_lds((gas_p)(const void*)(gBh + k0), (las_p)(void*)(&BsH[b][wid * 512]), 16, 0, 0);
        __builtin_amdgcn_global_load_lds((gas_p)(const void*)(gBl + k0), (las_p)(void*)(&BsL[b][wid * 512]), 16, 0, 0);
    };

    const int sl = kg ^ ((rsel >> 1) & 3);

    stage(0, 0);
    __syncthreads();
#pragma unroll 1
    for (int step = 0; step < 16; ++step) {
        const int cur = step & 1;
        if (step < 15) stage((step + 1) * 32, cur ^ 1);
        const f16x8* AH = (const f16x8*)AsH[cur];
        const f16x8* AL = (const f16x8*)AsL[cur];
        const f16x8* BH = (const f16x8*)BsH[cur];
        const f16x8* BL = (const f16x8*)BsL[cur];
        f16x8 bh[2], bl[2];
#pragma unroll
        for (int j = 0; j < 2; ++j) {
            int bi = (wn + j * 16 + rsel) * 4 + sl;
            bh[j] = BH[bi];
            bl[j] = BL[bi];
        }
#pragma unroll
        for (int i = 0; i < 4; ++i) {
            int ai = (wm + i * 16 + rsel) * 4 + sl;
            f16x8 ah = AH[ai];
            f16x8 al = AL[ai];
#pragma unroll
            for (int j = 0; j < 2; ++j) {
                acc0[i][j] = __builtin_amdgcn_mfma_f32_16x16x32_f16(ah, bh[j], acc0[i][j], 0, 0, 0);
                acc1[i][j] = __builtin_amdgcn_mfma_f32_16x16x32_f16(ah, bl[j], acc1[i][j], 0, 0, 0);
                acc1[i][j] = __builtin_amdgcn_mfma_f32_16x16x32_f16(al, bh[j], acc1[i][j], 0, 0, 0);
            }
        }
        __syncthreads();
    }

    // C/D layout: col=lane&15, row=(lane>>4)*4+reg  [HW-verified]
#pragma unroll
    for (int i = 0; i < 4; ++i) {
        int row0 = rowBase + wm + i * 16 + kg * 4;
#pragma unroll
        for (int j = 0; j < 2; ++j) {
            int col = bn + wn + j * 16 + rsel;
            float bb = bias[col];
#pragma unroll
            for (int r = 0; r < 4; ++r) {
                int row = row0 + r;
                if (row < rowEnd)
                    S.Y[(size_t)row * S.Nout + col] = acc0[i][j][r] + acc1[i][j][r] * (1.0f / 2048.0f) + bb;
            }
        }
    }
}

// ================= standalone paired GEMM launch (r8 verified) =================
struct GP {
    GSet s0, s1;
    const int* cntPtr;
    int cntScale0, cntScale1;
    int yT0;
};

__global__ __launch_bounds__(512, 4)
void gemm_pair(GP g)
{
    GSet S;
    int bn;
    if (blockIdx.y < (unsigned)g.yT0) {
        S = g.s0; S.nL = g.cntPtr[0] * g.cntScale0;
        bn = blockIdx.y * 128;
    } else {
        S = g.s1; S.nL = g.cntPtr[0] * g.cntScale1;
        bn = (blockIdx.y - g.yT0) * 128;
    }
    gemm_tile(S, blockIdx.x, bn);
}

// ================= shared context for combine/leaf =================
struct Ctx {
    GSet lv0, lv1;
    const int* cnt;
    const float *iou_pre, *fx_pre;
    float *iou_h, *fpre, *c_all, *h_all;
    const int *children, *lvlPerm, *lvlInv, *inv_g;
    const float *b_iouh_v, *b_iouh_l;
    _Float16 *hs_h, *hs_l, *ch_h, *ch_l;
};

// ================= combine+gather (levels 5,4; r8 verified) =================
__global__ __launch_bounds__(256)
void combine_gather(int sPar, int sLvl, Ctx m)
{
    int ip = blockIdx.x;
    int p = m.lvlPerm[sPar + ip];
    int t = threadIdx.x;
    int d0 = t * 2;
    float hsum[2] = {0.f, 0.f};
#pragma unroll
    for (int k = 0; k < 4; ++k) {
        int cnode = m.children[p * 4 + k];
        int j = m.lvlInv[cnode] - sLvl;
        int u = m.inv_g[cnode];
        size_t ub = (size_t)u * 1536;
        size_t jb = (size_t)j * 1536;
#pragma unroll
        for (int e = 0; e < 2; ++e) {
            int d = d0 + e;
            float iv = m.iou_pre[ub + d]        + m.iou_h[jb + d];
            float ov = m.iou_pre[ub + 512 + d]  + m.iou_h[jb + 512 + d];
            float uv = m.iou_pre[ub + 1024 + d] + m.iou_h[jb + 1024 + d];
            float fxn = m.fx_pre[(size_t)u * 512 + d];
            float csum = 0.f;
#pragma unroll
            for (int k2 = 0; k2 < 4; ++k2) {
                int gc = m.children[cnode * 4 + k2];
                float f = sigm(m.fpre[((size_t)(j * 4 + k2)) * 512 + d] + fxn);
                csum = fmaf(f, m.c_all[(size_t)gc * 512 + d], csum);
            }
            float cc = sigm(iv) * tanhf(uv) + csum;
            float hh = sigm(ov) * tanhf(cc);
            m.c_all[(size_t)cnode * 512 + d] = cc;
            m.h_all[(size_t)cnode * 512 + d] = hh;
            hsum[e] += hh;
            _Float16 hf = (_Float16)hh;
            size_t o = ((size_t)(ip * 4 + k)) * 512 + d;
            m.ch_h[o] = hf;
            m.ch_l[o] = (_Float16)((hh - (float)hf) * 2048.0f);
        }
    }
#pragma unroll
    for (int e = 0; e < 2; ++e) {
        _Float16 sh = (_Float16)hsum[e];
        m.hs_h[(size_t)ip * 512 + d0 + e] = sh;
        m.hs_l[(size_t)ip * 512 + d0 + e] = (_Float16)((hsum[e] - (float)sh) * 2048.0f);
    }
}

// ================= leaves + gather(level 5) (r8 verified) =================
__global__ __launch_bounds__(256)
void leaf_gather(Ctx m)
{
    int ip = blockIdx.x;
    int p = m.lvlPerm[341 + ip];
    int t = threadIdx.x;
    int d0 = t * 2;
    int nLg = m.cnt[0];
    float hsum[2] = {0.f, 0.f};
#pragma unroll
    for (int k = 0; k < 4; ++k) {
        int cnode = m.children[p * 4 + k];
        int u = m.inv_g[cnode];
        const float* bh = (u < nLg) ? m.b_iouh_l : m.b_iouh_v;
        size_t ub = (size_t)u * 1536;
#pragma unroll
        for (int e = 0; e < 2; ++e) {
            int d = d0 + e;
            float iv = m.iou_pre[ub + d]        + bh[d];
            float ov = m.iou_pre[ub + 512 + d]  + bh[512 + d];
            float uv = m.iou_pre[ub + 1024 + d] + bh[1024 + d];
            float cc = sigm(iv) * tanhf(uv);
            float hh = sigm(ov) * tanhf(cc);
            m.c_all[(size_t)cnode * 512 + d] = cc;
            m.h_all[(size_t)cnode * 512 + d] = hh;
            hsum[e] += hh;
            _Float16 hf = (_Float16)hh;
            size_t o = ((size_t)(ip * 4 + k)) * 512 + d;
            m.ch_h[o] = hf;
            m.ch_l[o] = (_Float16)((hh - (float)hf) * 2048.0f);
        }
    }
#pragma unroll
    for (int e = 0; e < 2; ++e) {
        _Float16 sh = (_Float16)hsum[e];
        m.hs_h[(size_t)ip * 512 + d0 + e] = sh;
        m.hs_l[(size_t)ip * 512 + d0 + e] = (_Float16)((hsum[e] - (float)sh) * 2048.0f);
    }
}

// ================= fused fp32 GEMV + combine for small levels (3,2,1,0) =================
// block = one node of the level. Phase A: sum children h (fp32, exact) into LDS.
// Phase B: 3584 dots (1536 iou_h + 4x512 fpre), B = fp16 hi + lo/2048 (v_fma_mix).
// Phase C: per-dim gate math, write c_all/h_all. No partition/perm needed.
struct GV {
    const float *iou_pre, *fx_pre;
    float *c_all, *h_all;
    const int *children, *inv_g;
    const int* cnt;
    const _Float16 *WiouhHl, *WiouhLl, *WiouhHv, *WiouhLv;
    const _Float16 *WfhHl, *WfhLl, *WfhHv, *WfhLv;
    const float *b_iouh_l, *b_iouh_v, *b_fh_l, *b_fh_v;
};

__global__ __launch_bounds__(512, 2)
void gemv_combine(int s, GV g)
{
    __shared__ float hsL[512];
    __shared__ float chL[4][512];
    __shared__ float cL[4][512];
    __shared__ float douts[3584];
    const int n = s + blockIdx.x;
    const int t = threadIdx.x;
    const int u = g.inv_g[n];
    const bool lang = u < g.cnt[0];

    int cn[4];
#pragma unroll
    for (int k = 0; k < 4; ++k) cn[k] = g.children[n * 4 + k];
    float hsv = 0.f;
#pragma unroll
    for (int k = 0; k < 4; ++k) {
        float hv = g.h_all[(size_t)cn[k] * 512 + t];
        chL[k][t] = hv;
        hsv += hv;
        cL[k][t] = g.c_all[(size_t)cn[k] * 512 + t];
    }
    hsL[t] = hsv;
    __syncthreads();

    const _Float16* WHi = lang ? g.WiouhHl : g.WiouhHv;
    const _Float16* WLi = lang ? g.WiouhLl : g.WiouhLv;
    const _Float16* WHf = lang ? g.WfhHl   : g.WfhHv;
    const _Float16* WLf = lang ? g.WfhLl   : g.WfhLv;

#pragma unroll
    for (int i = 0; i < 7; ++i) {
        const int o = i * 512 + t;
        const float* a;
        const _Float16 *bh, *bl;
        if (i < 3) {
            a = hsL;
            bh = WHi + (size_t)o * 512;
            bl = WLi + (size_t)o * 512;
        } else {
            a = chL[i - 3];
            bh = WHf + (size_t)t * 512;
            bl = WLf + (size_t)t * 512;
        }
        float accH = 0.f, accL = 0.f;
#pragma unroll 4
        for (int d = 0; d < 512; d += 8) {
            f16x8 vh = *(const f16x8*)(bh + d);
            f16x8 vl = *(const f16x8*)(bl + d);
#pragma unroll
            for (int j = 0; j < 8; ++j) {
                float av = a[d + j];
                accH = fmaf(av, (float)vh[j], accH);
                accL = fmaf(av, (float)vl[j], accL);
            }
        }
        douts[o] = accH + accL * (1.0f / 2048.0f);
    }
    __syncthreads();

    const float* b_iouh = lang ? g.b_iouh_l : g.b_iouh_v;
    const float* b_fh   = lang ? g.b_fh_l   : g.b_fh_v;
    size_t ub = (size_t)u * 1536;
    float iv = g.iou_pre[ub + t]        + douts[t]        + b_iouh[t];
    float ov = g.iou_pre[ub + 512 + t]  + douts[512 + t]  + b_iouh[512 + t];
    float uv = g.iou_pre[ub + 1024 + t] + douts[1024 + t] + b_iouh[1024 + t];
    float fxn = g.fx_pre[(size_t)u * 512 + t] + b_fh[t];
    float csum = 0.f;
#pragma unroll
    for (int k = 0; k < 4; ++k) {
        float f = sigm(douts[1536 + k * 512 + t] + fxn);
        csum = fmaf(f, cL[k][t], csum);
    }
    float cc = sigm(iv) * tanhf(uv) + csum;
    float hh = sigm(ov) * tanhf(cc);
    g.c_all[(size_t)n * 512 + t] = cc;
    g.h_all[(size_t)n * 512 + t] = hh;
}

// ================= fused: x -> fp16 hi/lo split + type-selector logits =================
__global__ __launch_bounds__(256)
void cast_x_sel(const float* __restrict__ x, const float* __restrict__ Wt,
                const float* __restrict__ bt,
                _Float16* __restrict__ hi, _Float16* __restrict__ lo,
                int* __restrict__ sel)
{
    __shared__ float s0[256], s1[256];
    int t = threadIdx.x;
    int row = blockIdx.x * 2 + (t >> 7);
    int c0 = (t & 127) * 4;
    float p0 = 0.f, p1 = 0.f;
    if (row < N_NODES) {
        size_t off = (size_t)row * 512 + c0;
        float4 v = *(const float4*)(x + off);
        float vv[4] = {v.x, v.y, v.z, v.w};
        union { _Float16 h[4]; ushort4 u; } H, L;
#pragma unroll
        for (int i = 0; i < 4; ++i) {
            _Float16 h = (_Float16)vv[i];
            H.h[i] = h;
            L.h[i] = (_Float16)((vv[i] - (float)h) * 2048.0f);
            p0 = fmaf(vv[i], Wt[(c0 + i) * 2], p0);
            p1 = fmaf(vv[i], Wt[(c0 + i) * 2 + 1], p1);
        }
        *(ushort4*)(hi + off) = H.u;
        *(ushort4*)(lo + off) = L.u;
    }
    s0[t] = p0; s1[t] = p1;
    __syncthreads();
    for (int st = 64; st > 0; st >>= 1) {
        if ((t & 127) < st) { s0[t] += s0[t + st]; s1[t] += s1[t + st]; }
        __syncthreads();
    }
    if ((t & 127) == 0 && row < N_NODES)
        sel[row] = (s0[t] + bt[0] >= s1[t] + bt[1]) ? 1 : 0;
}

// ================= prep: weight transpose+split (0..1535) | partition (1536..1542) =================
struct WtArgs {
    const float* src[8];
    _Float16* dsth[8];
    _Float16* dstl[8];
    int nout[8];
};

__global__ __launch_bounds__(256)
void prep(WtArgs a, const int* __restrict__ sel, int* __restrict__ perm_g,
          int* __restrict__ inv_g, int* __restrict__ lvlPerm,
          int* __restrict__ lvlInv, int* __restrict__ cnt)
{
    if (blockIdx.x < 1536) {
        int idx = blockIdx.x;
        int mi = idx / 192;
        int r = idx % 192;
        int n0 = (r >> 3) * 64;
        int k0 = (r & 7) * 64;
        int Nout = a.nout[mi];
        if (n0 >= Nout) return;
        const float* W = a.src[mi];
        _Float16* TH = a.dsth[mi];
        _Float16* TL = a.dstl[mi];
        __shared__ float tbuf[64][65];
        int tx = threadIdx.x & 63, ty = threadIdx.x >> 6;
#pragma unroll
        for (int rr = ty; rr < 64; rr += 4)
            tbuf[rr][tx] = W[(size_t)(k0 + rr) * Nout + n0 + tx];
        __syncthreads();
#pragma unroll
        for (int rr = ty; rr < 64; rr += 4) {
            float v = tbuf[tx][rr];
            _Float16 h = (_Float16)v;
            TH[(size_t)(n0 + rr) * 512 + k0 + tx] = h;
            TL[(size_t)(n0 + rr) * 512 + k0 + tx] = (_Float16)((v - (float)h) * 2048.0f);
        }
    } else {
        __shared__ int ps[256];
        int b = blockIdx.x - 1536;
        int s, e;
        if (b == 0) { s = 0; e = N_NODES; }
        else { s = d_STARTS[b - 1]; e = d_STARTS[b]; }
        int E = e - s;
        int t = threadIdx.x;
        int chunk = (E + 255) / 256;
        int beg = min(t * chunk, E);
        int end = min(beg + chunk, E);
        int c = 0;
        for (int i = beg; i < end; ++i) c += sel[s + i];
        ps[t] = c;
        __syncthreads();
        for (int off = 1; off < 256; off <<= 1) {
            int other = (t >= off) ? ps[t - off] : 0;
            __syncthreads();
            ps[t] += other;
            __syncthreads();
        }
        int total = ps[255];
        int excl = ps[t] - c;
        int pL = excl;
        int pV = total + (beg - excl);
        for (int i = beg; i < end; ++i) {
            int node = s + i;
            int pos = sel[node] ? pL++ : pV++;
            int slot = s + pos;
            if (b == 0) { perm_g[slot] = node; inv_g[node] = slot; }
            else { lvlPerm[slot] = node; lvlInv[node] = slot; }
        }
        if (t == 0) cnt[b] = total;
    }
}

extern "C" void kernel_launch(void* const* d_in, const int* in_sizes, int n_in,
                              void* d_out, int out_size, void* d_ws, size_t ws_size,
                              hipStream_t stream)
{
    const float* x        = (const float*)d_in[0];
    const int*   children = (const int*)  d_in[1];
    const float* W_ioux_v = (const float*)d_in[2];
    const float* b_ioux_v = (const float*)d_in[3];
    const float* W_iouh_v = (const float*)d_in[4];
    const float* b_iouh_v = (const float*)d_in[5];
    const float* W_fx_v   = (const float*)d_in[6];
    const float* b_fx_v   = (const float*)d_in[7];
    const float* W_fh_v   = (const float*)d_in[8];
    const float* b_fh_v   = (const float*)d_in[9];
    const float* W_ioux_l = (const float*)d_in[10];
    const float* b_ioux_l = (const float*)d_in[11];
    const float* W_iouh_l = (const float*)d_in[12];
    const float* b_iouh_l = (const float*)d_in[13];
    const float* W_fx_l   = (const float*)d_in[14];
    const float* b_fx_l   = (const float*)d_in[15];
    const float* W_fh_l   = (const float*)d_in[16];
    const float* b_fh_l   = (const float*)d_in[17];
    const float* W_type   = (const float*)d_in[18];
    const float* b_type   = (const float*)d_in[19];
    float* h_all = (float*)d_out;

    // ---- workspace carve-up ----
    float* p = (float*)d_ws;
    float* iou_pre = p; p += (size_t)N_NODES * 1536;
    float* fx_pre  = p; p += (size_t)N_NODES * 512;
    float* c_all   = p; p += (size_t)N_NODES * 512;
    float* iou_h   = p; p += (size_t)1024 * 1536;
    float* fpre    = p; p += (size_t)4096 * 512;
    int* sel     = (int*)p; p += 6144;
    int* perm_g  = (int*)p; p += 6144;
    int* inv_g   = (int*)p; p += 6144;
    int* lvlPerm = (int*)p; p += 2048;
    int* lvlInv  = (int*)p; p += 2048;
    int* cnt     = (int*)p; p += 64;
    _Float16* q = (_Float16*)p;
    _Float16* xh   = q; q += (size_t)N_NODES * 512;
    _Float16* xl   = q; q += (size_t)N_NODES * 512;
    _Float16* hs_h = q; q += (size_t)1024 * 512;
    _Float16* hs_l = q; q += (size_t)1024 * 512;
    _Float16* ch_h = q; q += (size_t)4096 * 512;
    _Float16* ch_l = q; q += (size_t)4096 * 512;
    _Float16* wt_ioux_vh = q; q += (size_t)1536 * 512;
    _Float16* wt_ioux_vl = q; q += (size_t)1536 * 512;
    _Float16* wt_ioux_lh = q; q += (size_t)1536 * 512;
    _Float16* wt_ioux_ll = q; q += (size_t)1536 * 512;
    _Float16* wt_iouh_vh = q; q += (size_t)1536 * 512;
    _Float16* wt_iouh_vl = q; q += (size_t)1536 * 512;
    _Float16* wt_iouh_lh = q; q += (size_t)1536 * 512;
    _Float16* wt_iouh_ll = q; q += (size_t)1536 * 512;
    _Float16* wt_fx_vh   = q; q += (size_t)512 * 512;
    _Float16* wt_fx_vl   = q; q += (size_t)512 * 512;
    _Float16* wt_fx_lh   = q; q += (size_t)512 * 512;
    _Float16* wt_fx_ll   = q; q += (size_t)512 * 512;
    _Float16* wt_fh_vh   = q; q += (size_t)512 * 512;
    _Float16* wt_fh_vl   = q; q += (size_t)512 * 512;
    _Float16* wt_fh_lh   = q; q += (size_t)512 * 512;
    _Float16* wt_fh_ll   = q; q += (size_t)512 * 512;

    cast_x_sel<<<(N_NODES + 1) / 2, 256, 0, stream>>>(x, W_type, b_type, xh, xl, sel);

    WtArgs wa;
    wa.src[0] = W_ioux_v; wa.dsth[0] = wt_ioux_vh; wa.dstl[0] = wt_ioux_vl; wa.nout[0] = 1536;
    wa.src[1] = W_ioux_l; wa.dsth[1] = wt_ioux_lh; wa.dstl[1] = wt_ioux_ll; wa.nout[1] = 1536;
    wa.src[2] = W_iouh_v; wa.dsth[2] = wt_iouh_vh; wa.dstl[2] = wt_iouh_vl; wa.nout[2] = 1536;
    wa.src[3] = W_iouh_l; wa.dsth[3] = wt_iouh_lh; wa.dstl[3] = wt_iouh_ll; wa.nout[3] = 1536;
    wa.src[4] = W_fx_v;   wa.dsth[4] = wt_fx_vh;   wa.dstl[4] = wt_fx_vl;   wa.nout[4] = 512;
    wa.src[5] = W_fx_l;   wa.dsth[5] = wt_fx_lh;   wa.dstl[5] = wt_fx_ll;   wa.nout[5] = 512;
    wa.src[6] = W_fh_v;   wa.dsth[6] = wt_fh_vh;   wa.dstl[6] = wt_fh_vl;   wa.nout[6] = 512;
    wa.src[7] = W_fh_l;   wa.dsth[7] = wt_fh_lh;   wa.dstl[7] = wt_fh_ll;   wa.nout[7] = 512;
    prep<<<1543, 256, 0, stream>>>(wa, sel, perm_g, inv_g, lvlPerm, lvlInv, cnt);

    // ---- shared context ----
    Ctx m{};
    m.lv0 = GSet{hs_h, hs_l, wt_iouh_lh, wt_iouh_ll, wt_iouh_vh, wt_iouh_vl,
                 b_iouh_l, b_iouh_v, iou_h, nullptr, 0, 0, 1536};
    m.lv1 = GSet{ch_h, ch_l, wt_fh_lh, wt_fh_ll, wt_fh_vh, wt_fh_vl,
                 b_fh_l, b_fh_v, fpre, nullptr, 0, 0, 512};
    m.cnt = cnt;
    m.iou_pre = iou_pre; m.fx_pre = fx_pre;
    m.iou_h = iou_h; m.fpre = fpre; m.c_all = c_all; m.h_all = h_all;
    m.children = children; m.lvlPerm = lvlPerm; m.lvlInv = lvlInv; m.inv_g = inv_g;
    m.b_iouh_v = b_iouh_v; m.b_iouh_l = b_iouh_l;
    m.hs_h = hs_h; m.hs_l = hs_l; m.ch_h = ch_h; m.ch_l = ch_l;

    // ---- precompute GEMMs (ioux 12 col-tiles + fx 4 col-tiles) ----
    {
        GP g{};
        g.s0 = GSet{xh, xl, wt_ioux_lh, wt_ioux_ll, wt_ioux_vh, wt_ioux_vl,
                    b_ioux_l, b_ioux_v, iou_pre, perm_g, 0, N_NODES, 1536};
        g.s1 = GSet{xh, xl, wt_fx_lh, wt_fx_ll, wt_fx_vh, wt_fx_vl,
                    b_fx_l, b_fx_v, fx_pre, perm_g, 0, N_NODES, 512};
        g.cntPtr = cnt; g.cntScale0 = 1; g.cntScale1 = 1; g.yT0 = 12;
        gemm_pair<<<dim3(44, 16), 512, 0, stream>>>(g);
    }

    // ---- leaves + gather(level 5) ----
    leaf_gather<<<1024, 256, 0, stream>>>(m);

    // ---- levels 5 and 4 (big): MFMA path ----
    static const int STARTS[8] = {0, 1, 5, 21, 85, 341, 1365, 5461};
    for (int l = 5; l >= 4; --l) {
        int s = STARTS[l];
        int E = STARTS[l + 1] - s;
        GP g{};
        g.s0 = m.lv0; g.s0.M = E;
        g.s1 = m.lv1; g.s1.M = E * 4;
        g.cntPtr = cnt + 1 + l; g.cntScale0 = 1; g.cntScale1 = 4; g.yT0 = 12;
        int gx = (E * 4 + 127) / 128 + 1;
        gemm_pair<<<dim3(gx, 16), 512, 0, stream>>>(g);
        combine_gather<<<STARTS[l] - STARTS[l - 1], 256, 0, stream>>>(STARTS[l - 1], s, m);
    }

    // ---- small levels 3..0: fused fp32 GEMV + combine, one launch per level ----
    GV gv{};
    gv.iou_pre = iou_pre; gv.fx_pre = fx_pre;
    gv.c_all = c_all; gv.h_all = h_all;
    gv.children = children; gv.inv_g = inv_g; gv.cnt = cnt;
    gv.WiouhHl = wt_iouh_lh; gv.WiouhLl = wt_iouh_ll;
    gv.WiouhHv = wt_iouh_vh; gv.WiouhLv = wt_iouh_vl;
    gv.WfhHl = wt_fh_lh; gv.WfhLl = wt_fh_ll;
    gv.WfhHv = wt_fh_vh; gv.WfhLv = wt_fh_vl;
    gv.b_iouh_l = b_iouh_l; gv.b_iouh_v = b_iouh_v;
    gv.b_fh_l = b_fh_l; gv.b_fh_v = b_fh_v;
    for (int l = 3; l >= 0; --l) {
        int s = STARTS[l];
        int E = STARTS[l + 1] - s;
        gemv_combine<<<E, 512, 0, stream>>>(s, gv);
    }
}

// Round 13
// 255.278 us; speedup vs baseline: 4.1231x; 4.1231x over previous
//
#include <hip/hip_runtime.h>
#include <cstdint>

constexpr int N_NODES = 5461;
constexpr int N_INTERIOR = 1365;

using f16x8 = __attribute__((ext_vector_type(8))) _Float16;
using f32x4 = __attribute__((ext_vector_type(4))) float;

typedef const __attribute__((address_space(1))) unsigned int* gas_p;
typedef __attribute__((address_space(3))) unsigned int* las_p;

__device__ __forceinline__ float sigm(float v) { return 1.0f / (1.0f + __expf(-v)); }

__constant__ int d_STARTS[8] = {0, 1, 5, 21, 85, 341, 1365, 5461};

// ---------------- paired, partitioned, double-buffered split-fp16 MFMA GEMM ----------------
// 512 threads = 8 waves (2M x 4N), wave tile 64x32, block tile 128x128, K=512 in 16 steps.
// LDS chunk-XOR swizzle (conflict-free, verified r7/r8): row r's 16B chunk c lives at slot
// c^((r>>1)&3); staged via inverse-permuted GLOBAL source (LDS dest linear); read slot
// kg^((rsel>>1)&3). SQ_LDS_BANK_CONFLICT == 0 measured.
// Rows [0,nL) use lang weights, [nL,M) vis; nL = cntPtr[0]*cntScale (device value).
struct GP {
    const _Float16* Ah[2]; const _Float16* Al[2];
    const _Float16* BhL[2]; const _Float16* BlL[2];
    const _Float16* BhV[2]; const _Float16* BlV[2];
    const float* biasL[2]; const float* biasV[2];
    float* Y[2];
    const int* permA[2];
    const int* cntPtr;
    int cntScale[2];
    int M[2]; int Nout[2]; int yT0;
};

__global__ __launch_bounds__(512, 4)
void gemm_pair(GP g)
{
    const int set = (blockIdx.y < (unsigned)g.yT0) ? 0 : 1;
    const int bn = (set ? (blockIdx.y - g.yT0) : blockIdx.y) * 128;
    const int M = g.M[set];
    const int nL = g.cntPtr[0] * g.cntScale[set];
    const int nTl = (nL + 127) >> 7;
    const int t = blockIdx.x;
    int rowBase, rowEnd;
    const _Float16 *Bh, *Bl;
    const float* bias;
    if (t < nTl) {
        rowBase = t << 7; rowEnd = nL;
        Bh = g.BhL[set]; Bl = g.BlL[set]; bias = g.biasL[set];
    } else {
        rowBase = nL + ((t - nTl) << 7); rowEnd = M;
        Bh = g.BhV[set]; Bl = g.BlV[set]; bias = g.biasV[set];
    }
    if (rowBase >= rowEnd) return;

    __shared__ _Float16 AsH[2][128 * 32];
    __shared__ _Float16 AsL[2][128 * 32];
    __shared__ _Float16 BsH[2][128 * 32];
    __shared__ _Float16 BsL[2][128 * 32];

    const int tid = threadIdx.x;
    const int wid = tid >> 6;          // 0..7
    const int lane = tid & 63;
    const int wm = (wid >> 2) * 64;    // 0 / 64
    const int wn = (wid & 3) * 32;     // 0 / 32 / 64 / 96
    const int rsel = lane & 15;
    const int kg = lane >> 4;          // 0..3

    // ---- staging: wave wid stages rows wid*16..wid*16+15 of each array ----
    // lane l -> row wid*16 + (l>>2), LDS slot l&3 (linear dest);
    // source chunk = (l&3) ^ ((l>>3)&3)  [= slot ^ ((row>>1)&3), row base mult of 16]
    const int lrow = lane >> 2;
    const int csrc = ((lane & 3) ^ ((lane >> 3) & 3)) * 8;   // halves
    const int* permA = g.permA[set];
    int aR = rowBase + wid * 16 + lrow; if (aR > rowEnd - 1) aR = rowEnd - 1;
    const int a0 = permA ? permA[aR] : aR;
    const _Float16* gAh = g.Ah[set] + (size_t)a0 * 512 + csrc;
    const _Float16* gAl = g.Al[set] + (size_t)a0 * 512 + csrc;
    const _Float16* gBh = Bh + (size_t)(bn + wid * 16 + lrow) * 512 + csrc;
    const _Float16* gBl = Bl + (size_t)(bn + wid * 16 + lrow) * 512 + csrc;

    f32x4 acc0[4][2] = {};
    f32x4 acc1[4][2] = {};

    auto stage = [&](int k0, int b) {
        __builtin_amdgcn_global_load_lds((gas_p)(const void*)(gAh + k0), (las_p)(void*)(&AsH[b][wid * 512]), 16, 0, 0);
        __builtin_amdgcn_global_load_lds((gas_p)(const void*)(gAl + k0), (las_p)(void*)(&AsL[b][wid * 512]), 16, 0, 0);
        __builtin_amdgcn_global_load_lds((gas_p)(const void*)(gBh + k0), (las_p)(void*)(&BsH[b][wid * 512]), 16, 0, 0);
        __builtin_amdgcn_global_load_lds((gas_p)(const void*)(gBl + k0), (las_p)(void*)(&BsL[b][wid * 512]), 16, 0, 0);
    };

    const int sl = kg ^ ((rsel >> 1) & 3);   // swizzled read slot (2-way banks = free)

    stage(0, 0);
    __syncthreads();                         // buf0 staged
#pragma unroll 1
    for (int step = 0; step < 16; ++step) {
        const int cur = step & 1;
        if (step < 15) stage((step + 1) * 32, cur ^ 1);   // prefetch next buf (hidden under compute)
        const f16x8* AH = (const f16x8*)AsH[cur];
        const f16x8* AL = (const f16x8*)AsL[cur];
        const f16x8* BH = (const f16x8*)BsH[cur];
        const f16x8* BL = (const f16x8*)BsL[cur];
        f16x8 bh[2], bl[2];
#pragma unroll
        for (int j = 0; j < 2; ++j) {
            int bi = (wn + j * 16 + rsel) * 4 + sl;
            bh[j] = BH[bi];
            bl[j] = BL[bi];
        }
#pragma unroll
        for (int i = 0; i < 4; ++i) {
            int ai = (wm + i * 16 + rsel) * 4 + sl;
            f16x8 ah = AH[ai];
            f16x8 al = AL[ai];
#pragma unroll
            for (int j = 0; j < 2; ++j) {
                acc0[i][j] = __builtin_amdgcn_mfma_f32_16x16x32_f16(ah, bh[j], acc0[i][j], 0, 0, 0);
                acc1[i][j] = __builtin_amdgcn_mfma_f32_16x16x32_f16(ah, bl[j], acc1[i][j], 0, 0, 0);
                acc1[i][j] = __builtin_amdgcn_mfma_f32_16x16x32_f16(al, bh[j], acc1[i][j], 0, 0, 0);
            }
        }
        __syncthreads();   // drains vmcnt(0): next buffer staged; all waves done reading cur
    }

    // C/D layout: col=lane&15, row=(lane>>4)*4+reg  [HW-verified]
    float* Y = g.Y[set];
    const int Nout = g.Nout[set];
#pragma unroll
    for (int i = 0; i < 4; ++i) {
        int row0 = rowBase + wm + i * 16 + kg * 4;
#pragma unroll
        for (int j = 0; j < 2; ++j) {
            int col = bn + wn + j * 16 + rsel;
            float bb = bias[col];
#pragma unroll
            for (int r = 0; r < 4; ++r) {
                int row = row0 + r;
                if (row < rowEnd)
                    Y[(size_t)row * Nout + col] = acc0[i][j][r] + acc1[i][j][r] * (1.0f / 2048.0f) + bb;
            }
        }
    }
}

// ---------------- fused: x -> fp16 hi/lo split + type-selector logits ----------------
__global__ __launch_bounds__(256)
void cast_x_sel(const float* __restrict__ x, const float* __restrict__ Wt,
                const float* __restrict__ bt,
                _Float16* __restrict__ hi, _Float16* __restrict__ lo,
                int* __restrict__ sel)
{
    __shared__ float s0[256], s1[256];
    int t = threadIdx.x;
    int row = blockIdx.x * 2 + (t >> 7);
    int c0 = (t & 127) * 4;
    float p0 = 0.f, p1 = 0.f;
    if (row < N_NODES) {
        size_t off = (size_t)row * 512 + c0;
        float4 v = *(const float4*)(x + off);
        float vv[4] = {v.x, v.y, v.z, v.w};
        union { _Float16 h[4]; ushort4 u; } H, L;
#pragma unroll
        for (int i = 0; i < 4; ++i) {
            _Float16 h = (_Float16)vv[i];
            H.h[i] = h;
            L.h[i] = (_Float16)((vv[i] - (float)h) * 2048.0f);
            p0 = fmaf(vv[i], Wt[(c0 + i) * 2], p0);
            p1 = fmaf(vv[i], Wt[(c0 + i) * 2 + 1], p1);
        }
        *(ushort4*)(hi + off) = H.u;
        *(ushort4*)(lo + off) = L.u;
    }
    s0[t] = p0; s1[t] = p1;
    __syncthreads();
    for (int st = 64; st > 0; st >>= 1) {
        if ((t & 127) < st) { s0[t] += s0[t + st]; s1[t] += s1[t + st]; }
        __syncthreads();
    }
    if ((t & 127) == 0 && row < N_NODES)
        sel[row] = (s0[t] + bt[0] >= s1[t] + bt[1]) ? 1 : 0;
}

// ---------------- transpose + split-cast all 8 weight matrices ----------------
struct WtArgs {
    const float* src[8];
    _Float16* dsth[8];
    _Float16* dstl[8];
    int nout[8];
};

__global__ __launch_bounds__(256)
void transpose_cast(WtArgs a)
{
    int mi = blockIdx.z;
    int Nout = a.nout[mi];
    int n0 = blockIdx.y * 64;
    if (n0 >= Nout) return;
    int k0 = blockIdx.x * 64;
    const float* W = a.src[mi];
    _Float16* TH = a.dsth[mi];
    _Float16* TL = a.dstl[mi];
    __shared__ float t[64][65];
    int tx = threadIdx.x & 63, ty = threadIdx.x >> 6;
#pragma unroll
    for (int r = ty; r < 64; r += 4)
        t[r][tx] = W[(size_t)(k0 + r) * Nout + n0 + tx];
    __syncthreads();
#pragma unroll
    for (int r = ty; r < 64; r += 4) {
        float v = t[tx][r];
        _Float16 h = (_Float16)v;
        TH[(size_t)(n0 + r) * 512 + k0 + tx] = h;
        TL[(size_t)(n0 + r) * 512 + k0 + tx] = (_Float16)((v - (float)h) * 2048.0f);
    }
}

// ---------------- stable sel-partition: block 0 -> global, blocks 1..6 -> levels 0..5 ----------------
__global__ __launch_bounds__(256)
void partition_kernel(const int* __restrict__ sel, int* __restrict__ perm_g,
                      int* __restrict__ inv_g, int* __restrict__ lvlPerm,
                      int* __restrict__ lvlInv, int* __restrict__ cnt)
{
    __shared__ int ps[256];
    int b = blockIdx.x;
    int s, e;
    if (b == 0) { s = 0; e = N_NODES; }
    else { s = d_STARTS[b - 1]; e = d_STARTS[b]; }
    int E = e - s;
    int t = threadIdx.x;
    int chunk = (E + 255) / 256;
    int beg = min(t * chunk, E);
    int end = min(beg + chunk, E);
    int c = 0;
    for (int i = beg; i < end; ++i) c += sel[s + i];
    ps[t] = c;
    __syncthreads();
    for (int off = 1; off < 256; off <<= 1) {
        int other = (t >= off) ? ps[t - off] : 0;
        __syncthreads();
        ps[t] += other;
        __syncthreads();
    }
    int total = ps[255];
    int excl = ps[t] - c;
    int pL = excl;
    int pV = total + (beg - excl);
    for (int i = beg; i < end; ++i) {
        int node = s + i;
        int pos = sel[node] ? pL++ : pV++;
        int slot = s + pos;
        if (b == 0) { perm_g[slot] = node; inv_g[node] = slot; }
        else { lvlPerm[slot] = node; lvlInv[node] = slot; }
    }
    if (t == 0) cnt[b] = total;
}

// ---------------- fused leaf-combine + gather(level 5) ----------------
__global__ __launch_bounds__(256)
void leaf_gather(const float* __restrict__ iou_pre,
                 const float* __restrict__ b_iouh_v, const float* __restrict__ b_iouh_l,
                 const int* __restrict__ children,
                 const int* __restrict__ lvlPerm, const int* __restrict__ inv_g,
                 const int* __restrict__ cnt,
                 float* __restrict__ c_all, float* __restrict__ h_all,
                 _Float16* __restrict__ hs_h, _Float16* __restrict__ hs_l,
                 _Float16* __restrict__ ch_h, _Float16* __restrict__ ch_l)
{
    int ip = blockIdx.x;
    int p = lvlPerm[341 + ip];
    int t = threadIdx.x;
    int d0 = t * 2;
    int nLg = cnt[0];
    float hsum[2] = {0.f, 0.f};
#pragma unroll
    for (int k = 0; k < 4; ++k) {
        int cnode = children[p * 4 + k];
        int u = inv_g[cnode];
        const float* bh = (u < nLg) ? b_iouh_l : b_iouh_v;
        size_t ub = (size_t)u * 1536;
#pragma unroll
        for (int e = 0; e < 2; ++e) {
            int d = d0 + e;
            float iv = iou_pre[ub + d]        + bh[d];
            float ov = iou_pre[ub + 512 + d]  + bh[512 + d];
            float uv = iou_pre[ub + 1024 + d] + bh[1024 + d];
            float cc = sigm(iv) * tanhf(uv);
            float hh = sigm(ov) * tanhf(cc);
            c_all[(size_t)cnode * 512 + d] = cc;
            h_all[(size_t)cnode * 512 + d] = hh;
            hsum[e] += hh;
            _Float16 hf = (_Float16)hh;
            size_t o = ((size_t)(ip * 4 + k)) * 512 + d;
            ch_h[o] = hf;
            ch_l[o] = (_Float16)((hh - (float)hf) * 2048.0f);
        }
    }
#pragma unroll
    for (int e = 0; e < 2; ++e) {
        _Float16 sh = (_Float16)hsum[e];
        hs_h[(size_t)ip * 512 + d0 + e] = sh;
        hs_l[(size_t)ip * 512 + d0 + e] = (_Float16)((hsum[e] - (float)sh) * 2048.0f);
    }
}

// ---------------- fused combine(level l) + gather(level l-1) ----------------
__global__ __launch_bounds__(256)
void combine_gather(int sPar, int sLvl,
    const float* __restrict__ iou_pre, const float* __restrict__ fx_pre,
    const float* __restrict__ iou_h, const float* __restrict__ fpre,
    const int* __restrict__ lvlPerm, const int* __restrict__ lvlInv,
    const int* __restrict__ inv_g, const int* __restrict__ children,
    float* __restrict__ c_all, float* __restrict__ h_all,
    _Float16* __restrict__ hs_h, _Float16* __restrict__ hs_l,
    _Float16* __restrict__ ch_h, _Float16* __restrict__ ch_l)
{
    int ip = blockIdx.x;
    int p = lvlPerm[sPar + ip];
    int t = threadIdx.x;
    int d0 = t * 2;
    float hsum[2] = {0.f, 0.f};
#pragma unroll
    for (int k = 0; k < 4; ++k) {
        int cnode = children[p * 4 + k];
        int j = lvlInv[cnode] - sLvl;
        int u = inv_g[cnode];
        size_t ub = (size_t)u * 1536;
        size_t jb = (size_t)j * 1536;
#pragma unroll
        for (int e = 0; e < 2; ++e) {
            int d = d0 + e;
            float iv = iou_pre[ub + d]        + iou_h[jb + d];
            float ov = iou_pre[ub + 512 + d]  + iou_h[jb + 512 + d];
            float uv = iou_pre[ub + 1024 + d] + iou_h[jb + 1024 + d];
            float fxn = fx_pre[(size_t)u * 512 + d];
            float csum = 0.f;
#pragma unroll
            for (int k2 = 0; k2 < 4; ++k2) {
                int gc = children[cnode * 4 + k2];
                float f = sigm(fpre[((size_t)(j * 4 + k2)) * 512 + d] + fxn);
                csum = fmaf(f, c_all[(size_t)gc * 512 + d], csum);
            }
            float cc = sigm(iv) * tanhf(uv) + csum;
            float hh = sigm(ov) * tanhf(cc);
            c_all[(size_t)cnode * 512 + d] = cc;
            h_all[(size_t)cnode * 512 + d] = hh;
            hsum[e] += hh;
            _Float16 hf = (_Float16)hh;
            size_t o = ((size_t)(ip * 4 + k)) * 512 + d;
            ch_h[o] = hf;
            ch_l[o] = (_Float16)((hh - (float)hf) * 2048.0f);
        }
    }
#pragma unroll
    for (int e = 0; e < 2; ++e) {
        _Float16 sh = (_Float16)hsum[e];
        hs_h[(size_t)ip * 512 + d0 + e] = sh;
        hs_l[(size_t)ip * 512 + d0 + e] = (_Float16)((hsum[e] - (float)sh) * 2048.0f);
    }
}

// ---------------- root combine (level 0) ----------------
__global__ __launch_bounds__(256)
void combine_root(
    const float* __restrict__ iou_pre, const float* __restrict__ fx_pre,
    const float* __restrict__ iou_h, const float* __restrict__ fpre,
    const int* __restrict__ inv_g, const int* __restrict__ children,
    float* __restrict__ c_all, float* __restrict__ h_all)
{
    int d = blockIdx.x * 256 + threadIdx.x;
    if (d >= 512) return;
    int u = inv_g[0];
    size_t ub = (size_t)u * 1536;
    float iv = iou_pre[ub + d]        + iou_h[d];
    float ov = iou_pre[ub + 512 + d]  + iou_h[512 + d];
    float uv = iou_pre[ub + 1024 + d] + iou_h[1024 + d];
    float fxn = fx_pre[(size_t)u * 512 + d];
    float csum = 0.f;
#pragma unroll
    for (int k = 0; k < 4; ++k) {
        int gc = children[k];
        float f = sigm(fpre[(size_t)k * 512 + d] + fxn);
        csum = fmaf(f, c_all[(size_t)gc * 512 + d], csum);
    }
    float cc = sigm(iv) * tanhf(uv) + csum;
    float hh = sigm(ov) * tanhf(cc);
    c_all[d] = cc;
    h_all[d] = hh;
}

extern "C" void kernel_launch(void* const* d_in, const int* in_sizes, int n_in,
                              void* d_out, int out_size, void* d_ws, size_t ws_size,
                              hipStream_t stream)
{
    const float* x        = (const float*)d_in[0];
    const int*   children = (const int*)  d_in[1];
    const float* W_ioux_v = (const float*)d_in[2];
    const float* b_ioux_v = (const float*)d_in[3];
    const float* W_iouh_v = (const float*)d_in[4];
    const float* b_iouh_v = (const float*)d_in[5];
    const float* W_fx_v   = (const float*)d_in[6];
    const float* b_fx_v   = (const float*)d_in[7];
    const float* W_fh_v   = (const float*)d_in[8];
    const float* b_fh_v   = (const float*)d_in[9];
    const float* W_ioux_l = (const float*)d_in[10];
    const float* b_ioux_l = (const float*)d_in[11];
    const float* W_iouh_l = (const float*)d_in[12];
    const float* b_iouh_l = (const float*)d_in[13];
    const float* W_fx_l   = (const float*)d_in[14];
    const float* b_fx_l   = (const float*)d_in[15];
    const float* W_fh_l   = (const float*)d_in[16];
    const float* b_fh_l   = (const float*)d_in[17];
    const float* W_type   = (const float*)d_in[18];
    const float* b_type   = (const float*)d_in[19];
    float* h_all = (float*)d_out;

    // ---- workspace carve-up ----
    float* p = (float*)d_ws;
    float* iou_pre = p; p += (size_t)N_NODES * 1536;
    float* fx_pre  = p; p += (size_t)N_NODES * 512;
    float* c_all   = p; p += (size_t)N_NODES * 512;
    float* iou_h   = p; p += (size_t)1024 * 1536;
    float* fpre    = p; p += (size_t)4096 * 512;
    int* sel     = (int*)p; p += 6144;
    int* perm_g  = (int*)p; p += 6144;
    int* inv_g   = (int*)p; p += 6144;
    int* lvlPerm = (int*)p; p += 2048;
    int* lvlInv  = (int*)p; p += 2048;
    int* cnt     = (int*)p; p += 64;
    _Float16* q = (_Float16*)p;
    _Float16* xh   = q; q += (size_t)N_NODES * 512;
    _Float16* xl   = q; q += (size_t)N_NODES * 512;
    _Float16* hs_h = q; q += (size_t)1024 * 512;
    _Float16* hs_l = q; q += (size_t)1024 * 512;
    _Float16* ch_h = q; q += (size_t)4096 * 512;
    _Float16* ch_l = q; q += (size_t)4096 * 512;
    _Float16* wt_ioux_vh = q; q += (size_t)1536 * 512;
    _Float16* wt_ioux_vl = q; q += (size_t)1536 * 512;
    _Float16* wt_ioux_lh = q; q += (size_t)1536 * 512;
    _Float16* wt_ioux_ll = q; q += (size_t)1536 * 512;
    _Float16* wt_iouh_vh = q; q += (size_t)1536 * 512;
    _Float16* wt_iouh_vl = q; q += (size_t)1536 * 512;
    _Float16* wt_iouh_lh = q; q += (size_t)1536 * 512;
    _Float16* wt_iouh_ll = q; q += (size_t)1536 * 512;
    _Float16* wt_fx_vh   = q; q += (size_t)512 * 512;
    _Float16* wt_fx_vl   = q; q += (size_t)512 * 512;
    _Float16* wt_fx_lh   = q; q += (size_t)512 * 512;
    _Float16* wt_fx_ll   = q; q += (size_t)512 * 512;
    _Float16* wt_fh_vh   = q; q += (size_t)512 * 512;
    _Float16* wt_fh_vl   = q; q += (size_t)512 * 512;
    _Float16* wt_fh_lh   = q; q += (size_t)512 * 512;
    _Float16* wt_fh_ll   = q; q += (size_t)512 * 512;

    cast_x_sel<<<(N_NODES + 1) / 2, 256, 0, stream>>>(x, W_type, b_type, xh, xl, sel);

    WtArgs wa;
    wa.src[0] = W_ioux_v; wa.dsth[0] = wt_ioux_vh; wa.dstl[0] = wt_ioux_vl; wa.nout[0] = 1536;
    wa.src[1] = W_ioux_l; wa.dsth[1] = wt_ioux_lh; wa.dstl[1] = wt_ioux_ll; wa.nout[1] = 1536;
    wa.src[2] = W_iouh_v; wa.dsth[2] = wt_iouh_vh; wa.dstl[2] = wt_iouh_vl; wa.nout[2] = 1536;
    wa.src[3] = W_iouh_l; wa.dsth[3] = wt_iouh_lh; wa.dstl[3] = wt_iouh_ll; wa.nout[3] = 1536;
    wa.src[4] = W_fx_v;   wa.dsth[4] = wt_fx_vh;   wa.dstl[4] = wt_fx_vl;   wa.nout[4] = 512;
    wa.src[5] = W_fx_l;   wa.dsth[5] = wt_fx_lh;   wa.dstl[5] = wt_fx_ll;   wa.nout[5] = 512;
    wa.src[6] = W_fh_v;   wa.dsth[6] = wt_fh_vh;   wa.dstl[6] = wt_fh_vl;   wa.nout[6] = 512;
    wa.src[7] = W_fh_l;   wa.dsth[7] = wt_fh_lh;   wa.dstl[7] = wt_fh_ll;   wa.nout[7] = 512;
    transpose_cast<<<dim3(8, 24, 8), 256, 0, stream>>>(wa);

    partition_kernel<<<7, 256, 0, stream>>>(sel, perm_g, inv_g, lvlPerm, lvlInv, cnt);

    // ---- precompute GEMMs: set0 = ioux (Nout 1536), set1 = fx (Nout 512) ----
    {
        GP g{};
        g.Ah[0] = xh; g.Al[0] = xl;       g.Ah[1] = xh; g.Al[1] = xl;
        g.BhL[0] = wt_ioux_lh; g.BlL[0] = wt_ioux_ll; g.BhV[0] = wt_ioux_vh; g.BlV[0] = wt_ioux_vl;
        g.BhL[1] = wt_fx_lh;   g.BlL[1] = wt_fx_ll;   g.BhV[1] = wt_fx_vh;   g.BlV[1] = wt_fx_vl;
        g.biasL[0] = b_ioux_l; g.biasV[0] = b_ioux_v;
        g.biasL[1] = b_fx_l;   g.biasV[1] = b_fx_v;
        g.Y[0] = iou_pre; g.Y[1] = fx_pre;
        g.permA[0] = perm_g; g.permA[1] = perm_g;
        g.cntPtr = cnt; g.cntScale[0] = 1; g.cntScale[1] = 1;
        g.M[0] = N_NODES; g.M[1] = N_NODES;
        g.Nout[0] = 1536; g.Nout[1] = 512;
        g.yT0 = 12;
        gemm_pair<<<dim3(44, 16), 512, 0, stream>>>(g);
    }

    // ---- leaves fused with gather for level 5 ----
    leaf_gather<<<1024, 256, 0, stream>>>(iou_pre, b_iouh_v, b_iouh_l, children,
        lvlPerm, inv_g, cnt, c_all, h_all, hs_h, hs_l, ch_h, ch_l);

    // ---- interior levels bottom-up ----
    static const int STARTS[8] = {0, 1, 5, 21, 85, 341, 1365, 5461};
    for (int l = 5; l >= 0; --l) {
        int s = STARTS[l];
        int E = STARTS[l + 1] - s;
        GP g{};
        g.Ah[0] = hs_h; g.Al[0] = hs_l;   g.Ah[1] = ch_h; g.Al[1] = ch_l;
        g.BhL[0] = wt_iouh_lh; g.BlL[0] = wt_iouh_ll; g.BhV[0] = wt_iouh_vh; g.BlV[0] = wt_iouh_vl;
        g.BhL[1] = wt_fh_lh;   g.BlL[1] = wt_fh_ll;   g.BhV[1] = wt_fh_vh;   g.BlV[1] = wt_fh_vl;
        g.biasL[0] = b_iouh_l; g.biasV[0] = b_iouh_v;
        g.biasL[1] = b_fh_l;   g.biasV[1] = b_fh_v;
        g.Y[0] = iou_h; g.Y[1] = fpre;
        g.permA[0] = nullptr; g.permA[1] = nullptr;
        g.cntPtr = cnt + 1 + l; g.cntScale[0] = 1; g.cntScale[1] = 4;
        g.M[0] = E; g.M[1] = E * 4;
        g.Nout[0] = 1536; g.Nout[1] = 512;
        g.yT0 = 12;
        int gx = 1 + (E * 4 + 127) / 128;
        gemm_pair<<<dim3(gx, 16), 512, 0, stream>>>(g);
        if (l > 0) {
            int sPar = STARTS[l - 1];
            int nPar = s - sPar;
            combine_gather<<<nPar, 256, 0, stream>>>(sPar, s,
                iou_pre, fx_pre, iou_h, fpre, lvlPerm, lvlInv, inv_g, children,
                c_all, h_all, hs_h, hs_l, ch_h, ch_l);
        } else {
            combine_root<<<2, 256, 0, stream>>>(iou_pre, fx_pre, iou_h, fpre,
                inv_g, children, c_all, h_all);
        }
    }
}